// Round 7
// baseline (188.783 us; speedup 1.0000x reference)
//
#include <hip/hip_runtime.h>
#include <hip/hip_bf16.h>
#include <math.h>

// ---------------------------------------------------------------------------
// Sketched CNN-MNIST forward, MFMA end-to-end.
// conv1: MFMA, taps t=ki*6+kj (K=30 pad 32); even-aligned b32 A-reads; odd
//        output columns via kj-shifted weights (2nd MFMA), pool picks regs.
// conv2: h1 in LDS as [img*4+icgrp][pos][8ic] (uniform bank load, aligned);
//        wave = (pool-row, img-pair) x all 4 n-tiles -> 1 A-read : 4 MFMA
//        (halves LDS traffic vs R6). 4 img/block, 3 blocks/CU.
// fc:    fused fc1 (16 waves x 32-col MFMA strips, A-tile in LDS) +
//        fc2 + log_softmax (1 image/wave, full-wave shuffle reduce).
// ---------------------------------------------------------------------------

typedef __attribute__((ext_vector_type(8))) short bf16x8;
typedef __attribute__((ext_vector_type(4))) float f32x4;

static __device__ inline ushort f2bfu(float v) {
    union { __hip_bfloat16 h; ushort u; } cv;
    cv.h = __float2bfloat16(v);
    return cv.u;
}

// ws layout (bytes):
//   wc1b bf16 [32 oc][32 t]  t=ki*6+kj       [0,       2048)
//   wc1s bf16 [32 oc][32 t]  kj-shifted      [2048,    4096)
//   wc2b bf16 [64 oc][25 tap][32 ic]         [4096,    106496)
//   W3   bf16 [512][1024]                    [106496,  1155072)
//   h2   bf16 [B][1024]                      [1155072, +B*2048)

__global__ __launch_bounds__(256)
void k_reconstruct(const float* __restrict__ w1, const float* __restrict__ w2,
                   const float* __restrict__ w3,
                   const int* __restrict__ hi1, const int* __restrict__ hi2,
                   const int* __restrict__ hi3,
                   const float* __restrict__ s1, const float* __restrict__ s2,
                   const float* __restrict__ s3,
                   __hip_bfloat16* __restrict__ wc1b,
                   __hip_bfloat16* __restrict__ wc1s,
                   __hip_bfloat16* __restrict__ wc2b,
                   __hip_bfloat16* __restrict__ W3) {
    int i = blockIdx.x * blockDim.x + threadIdx.x;
    if (i < 1024) {
        int oc = i >> 5, t = i & 31;
        int ki = (t * 43) >> 8;            // t / 6
        int kj = t - 6 * ki;
        float v = 0.f;
        if (ki < 5 && kj < 5) {
            int f = ki * 5 + kj;
            v = w1[oc * 128 + hi1[f]] * s1[f];
        }
        wc1b[i] = __float2bfloat16(v);
    } else if (i < 2048) {                 // kj-shifted conv1 weights
        int j = i - 1024;
        int oc = j >> 5, t = j & 31;
        int ki = (t * 43) >> 8;
        int kj = t - 6 * ki;
        float v = 0.f;
        if (ki < 5 && kj >= 1) {           // kj in 1..5 -> real tap kj-1
            int f = ki * 5 + (kj - 1);
            v = w1[oc * 128 + hi1[f]] * s1[f];
        }
        wc1s[j] = __float2bfloat16(v);
    } else if (i < 53248) {
        int j = i - 2048;
        int oc = j / 800, r = j % 800;
        int tap = r >> 5, ic = r & 31;
        int f = ic * 25 + tap;             // original sketch index
        wc2b[j] = __float2bfloat16(w2[oc * 128 + hi2[f]] * s2[f]);
    } else if (i < 577536) {
        int j = i - 53248;
        int r = j >> 10, k = j & 1023;
        W3[j] = __float2bfloat16(w3[r * 128 + hi3[k]] * s3[k]);
    }
}

// 4 images per block, 8 waves, 3 blocks/CU (LDS 43.6 KB).
// h1 layout: section s = img*4 + (ic>>3); s_h1[s*1160 + pos*8 + (ic&7)].
__global__ __launch_bounds__(512, 6)
void k_conv(const float* __restrict__ x,
            const __hip_bfloat16* __restrict__ wc1b,
            const __hip_bfloat16* __restrict__ wc1s,
            const __hip_bfloat16* __restrict__ wc2b,
            const float* __restrict__ b1, const float* __restrict__ b2,
            __hip_bfloat16* __restrict__ h2) {
    __shared__ __align__(16) ushort s_xb[4 * 816];     // bf16 images (+pad)
    __shared__ __align__(16) ushort s_h1[16 * 1160];   // sectioned, 37.1 KB

    const int tid = threadIdx.x;
    const int b0 = blockIdx.x * 4;
    const int wave = tid >> 6, lane = tid & 63;
    const int l15 = lane & 15, quad = lane >> 4;

    // ---- stage 4 images as bf16 (coalesced float4) ----
    {
        const float4* xg = (const float4*)(x + (size_t)b0 * 784);
        for (int i = tid; i < 784; i += 512) {
            float4 v = xg[i];
            int img = i / 196;
            int pos = (i - img * 196) * 4;
            ushort* dst = &s_xb[img * 816 + pos];
            dst[0] = f2bfu(v.x); dst[1] = f2bfu(v.y);
            dst[2] = f2bfu(v.z); dst[3] = f2bfu(v.w);
        }
        if (tid < 128) {                    // zero pad (read by pad taps, w=0)
            int img = tid >> 5, k = tid & 31;
            s_xb[img * 816 + 784 + k] = 0;
        }
    }

    // conv1 B-fragments (normal + shifted) + biases (tiny, L2-resident)
    bf16x8 bw1[2], bw1s[2];
    float bb1[2];
    #pragma unroll
    for (int nt = 0; nt < 2; ++nt) {
        bw1[nt]  = *(const bf16x8*)((const ushort*)wc1b + (nt * 16 + l15) * 32 + quad * 8);
        bw1s[nt] = *(const bf16x8*)((const ushort*)wc1s + (nt * 16 + l15) * 32 + quad * 8);
        bb1[nt] = b1[nt * 16 + l15];
    }
    __syncthreads();

    // ---- conv1 via MFMA: wave = (img, half). M=576 pool-grouped, N=32 ----
    {
        const int img = wave >> 1, half = wave & 1;
        const int sub = l15 & 3;
        const ushort* srcImg = s_xb + img * 816;
        int offr[4];
        #pragma unroll
        for (int r = 0; r < 4; ++r) {
            int t = quad * 8 + 2 * r;          // even
            int row = (t * 43) >> 8;           // t / 6
            int col = t - 6 * row;             // even
            offr[r] = row * 28 + col;          // even
        }
        const int g0 = l15 >> 3, r0 = l15 & 7;
        #pragma unroll
        for (int ii = 0; ii < 18; ++ii) {
            const int i = half * 18 + ii;
            const int pb = 4 * i + (l15 >> 2);
            const int pi = (pb * 171) >> 11;   // pb / 12
            const int pj = pb - 12 * pi;
            const int base_e = (2 * pi + (sub >> 1)) * 28 + 2 * pj;   // even
            const ushort* p0 = srcImg + base_e;
            union { bf16x8 v; uint u[4]; } A;
            A.u[0] = *(const uint*)(p0 + offr[0]);
            A.u[1] = *(const uint*)(p0 + offr[1]);
            A.u[2] = *(const uint*)(p0 + offr[2]);
            A.u[3] = *(const uint*)(p0 + offr[3]);
            f32x4 z = {0.f, 0.f, 0.f, 0.f};
            f32x4 ce0 = __builtin_amdgcn_mfma_f32_16x16x32_bf16(A.v, bw1[0],  z, 0, 0, 0);
            f32x4 co0 = __builtin_amdgcn_mfma_f32_16x16x32_bf16(A.v, bw1s[0], z, 0, 0, 0);
            f32x4 ce1 = __builtin_amdgcn_mfma_f32_16x16x32_bf16(A.v, bw1[1],  z, 0, 0, 0);
            f32x4 co1 = __builtin_amdgcn_mfma_f32_16x16x32_bf16(A.v, bw1s[1], z, 0, 0, 0);
            const int pbo = 4 * i + quad;
            float m0 = fmaxf(fmaxf(ce0[0], co0[1]), fmaxf(ce0[2], co0[3]));
            float m1 = fmaxf(fmaxf(ce1[0], co1[1]), fmaxf(ce1[2], co1[3]));
            // oc = l15 -> section img*4 + g0 ; oc = 16+l15 -> section img*4+2+g0
            s_h1[(img * 4 + g0) * 1160 + pbo * 8 + r0]     = f2bfu(fmaxf(m0 + bb1[0], 0.f));
            s_h1[(img * 4 + 2 + g0) * 1160 + pbo * 8 + r0] = f2bfu(fmaxf(m1 + bb1[1], 0.f));
        }
    }
    __syncthreads();

    // ---- conv2: 25 tap-GEMMs, K=ic=32; wave = (pool-row, img-pair) ----
    // Each wave: 2 images x all 4 n-tiles -> each A ds_read feeds 4 MFMAs.
    const int pr = wave & 3, ip = wave >> 2;
    const int sub2 = l15 & 3;
    const int ci2 = 2 * pr + (sub2 >> 1);
    const int cj2 = 2 * (l15 >> 2) + (sub2 & 1);
    const int posBase = (ci2 * 12 + cj2) * 8;
    const int abase0 = ((2 * ip)     * 4 + quad) * 1160 + posBase;
    const int abase1 = ((2 * ip + 1) * 4 + quad) * 1160 + posBase;
    const ushort* bP = (const ushort*)wc2b + quad * 8;

    f32x4 acc[2][4];                       // [img-in-pair][nt]
    float bb2[4];
    #pragma unroll
    for (int nt = 0; nt < 4; ++nt) {
        bb2[nt] = b2[nt * 16 + l15];
        acc[0][nt] = (f32x4){0.f, 0.f, 0.f, 0.f};
        acc[1][nt] = (f32x4){0.f, 0.f, 0.f, 0.f};
    }

    #pragma unroll
    for (int tap = 0; tap < 25; ++tap) {
        const int ki = tap / 5, kj = tap % 5;          // compile-time
        const int off = (ki * 12 + kj) * 8;
        bf16x8 a0 = *(const bf16x8*)&s_h1[abase0 + off];
        bf16x8 a1 = *(const bf16x8*)&s_h1[abase1 + off];
        #pragma unroll
        for (int nt = 0; nt < 4; ++nt) {
            bf16x8 bf = *(const bf16x8*)(bP + (nt * 16 + l15) * 800 + tap * 32);
            acc[0][nt] = __builtin_amdgcn_mfma_f32_16x16x32_bf16(a0, bf, acc[0][nt], 0, 0, 0);
            acc[1][nt] = __builtin_amdgcn_mfma_f32_16x16x32_bf16(a1, bf, acc[1][nt], 0, 0, 0);
        }
    }

    // D rows m = quad*4+r -> (pool row = pr, pool col = quad), max over r
    #pragma unroll
    for (int i2 = 0; i2 < 2; ++i2) {
        const int img = 2 * ip + i2;
        #pragma unroll
        for (int nt = 0; nt < 4; ++nt) {
            f32x4 c = acc[i2][nt];
            float m = fmaxf(fmaxf(c[0], c[1]), fmaxf(c[2], c[3]));
            float v = fmaxf(m + bb2[nt], 0.f);
            h2[(size_t)(b0 + img) * 1024 + (nt * 16 + l15) * 16 + pr * 4 + quad] =
                __float2bfloat16(v);
        }
    }
}

// Fused fc1 (bf16 MFMA) + fc2 + log_softmax. 1024 thr = 16 waves;
// fc1: wave = 32-col strip; fc2: wave = 1 image, full-wave shuffle reduce.
__global__ __launch_bounds__(1024)
void k_fc(const __hip_bfloat16* __restrict__ A, const __hip_bfloat16* __restrict__ Bw,
          const float* __restrict__ b3, const float* __restrict__ fc2w,
          const float* __restrict__ fc2b, float* __restrict__ out) {
    __shared__ __align__(16) ushort s_A[16 * 1032];   // +8 pad per row
    __shared__ float s_h3[16 * 516];

    const int tid = threadIdx.x;
    const int wave = tid >> 6, lane = tid & 63;
    const int l15 = lane & 15, quad = lane >> 4;
    const int mBase = blockIdx.x * 16;
    const int nBase = wave * 32;

    // stage A row `wave` into LDS (64 lanes x 32 B = 2 KB row)
    {
        const uint4* g = (const uint4*)(A + (size_t)(mBase + wave) * 1024);
        uint4 v0 = g[lane * 2], v1 = g[lane * 2 + 1];
        uint4* d = (uint4*)&s_A[wave * 1032 + lane * 16];
        d[0] = v0; d[1] = v1;
    }
    __syncthreads();

    f32x4 acc[2];
    acc[0] = (f32x4){0.f, 0.f, 0.f, 0.f};
    acc[1] = (f32x4){0.f, 0.f, 0.f, 0.f};

    const ushort* aP = &s_A[l15 * 1032 + quad * 8];
    const __hip_bfloat16* bP = Bw + (size_t)(nBase + l15) * 1024 + quad * 8;
    #pragma unroll 4
    for (int kt = 0; kt < 32; ++kt) {
        bf16x8 a = *(const bf16x8*)(aP + kt * 32);
        bf16x8 bf0 = *(const bf16x8*)(bP + kt * 32);
        bf16x8 bf1 = *(const bf16x8*)(bP + (size_t)16 * 1024 + kt * 32);
        acc[0] = __builtin_amdgcn_mfma_f32_16x16x32_bf16(a, bf0, acc[0], 0, 0, 0);
        acc[1] = __builtin_amdgcn_mfma_f32_16x16x32_bf16(a, bf1, acc[1], 0, 0, 0);
    }

    #pragma unroll
    for (int ntl = 0; ntl < 2; ++ntl) {
        int col = nBase + ntl * 16 + l15;
        float bb = b3[col];
        #pragma unroll
        for (int r = 0; r < 4; ++r)
            s_h3[(quad * 4 + r) * 516 + col] = fmaxf(acc[ntl][r] + bb, 0.f);
    }
    __syncthreads();

    // ---- fc2 + log_softmax: wave handles image `wave` ----
    const float* hrow = &s_h3[wave * 516];
    float4 h0 = *(const float4*)&hrow[lane * 8];
    float4 h1 = *(const float4*)&hrow[lane * 8 + 4];
    float lg[10];
    #pragma unroll
    for (int c = 0; c < 10; ++c) {
        float4 w0 = *(const float4*)&fc2w[c * 512 + lane * 8];
        float4 w1 = *(const float4*)&fc2w[c * 512 + lane * 8 + 4];
        float s = h0.x * w0.x + h0.y * w0.y + h0.z * w0.z + h0.w * w0.w
                + h1.x * w1.x + h1.y * w1.y + h1.z * w1.z + h1.w * w1.w;
        s += __shfl_down(s, 32);
        s += __shfl_down(s, 16);
        s += __shfl_down(s, 8);
        s += __shfl_down(s, 4);
        s += __shfl_down(s, 2);
        s += __shfl_down(s, 1);
        lg[c] = s;
    }
    if (lane == 0) {
        float mx = -1e30f;
        #pragma unroll
        for (int c = 0; c < 10; ++c) { lg[c] += fc2b[c]; mx = fmaxf(mx, lg[c]); }
        float sum = 0.f;
        #pragma unroll
        for (int c = 0; c < 10; ++c) sum += expf(lg[c] - mx);
        float lse = mx + logf(sum);
        #pragma unroll
        for (int c = 0; c < 10; ++c)
            out[(size_t)(mBase + wave) * 10 + c] = lg[c] - lse;
    }
}

extern "C" void kernel_launch(void* const* d_in, const int* in_sizes, int n_in,
                              void* d_out, int out_size, void* d_ws, size_t ws_size,
                              hipStream_t stream) {
    const float* x    = (const float*)d_in[0];
    const int*   hi1  = (const int*)d_in[1];
    const int*   hi2  = (const int*)d_in[2];
    const int*   hi3  = (const int*)d_in[3];
    const float* s1   = (const float*)d_in[4];
    const float* s2   = (const float*)d_in[5];
    const float* s3   = (const float*)d_in[6];
    const float* w1   = (const float*)d_in[7];
    const float* b1   = (const float*)d_in[8];
    const float* w2   = (const float*)d_in[9];
    const float* b2   = (const float*)d_in[10];
    const float* w3   = (const float*)d_in[11];
    const float* b3   = (const float*)d_in[12];
    const float* fc2w = (const float*)d_in[13];
    const float* fc2b = (const float*)d_in[14];
    float* out = (float*)d_out;

    const int B = in_sizes[0] / 784;   // 4096

    char* ws = (char*)d_ws;
    __hip_bfloat16* wc1b = (__hip_bfloat16*)(ws + 0);
    __hip_bfloat16* wc1s = (__hip_bfloat16*)(ws + 2048);
    __hip_bfloat16* wc2b = (__hip_bfloat16*)(ws + 4096);
    __hip_bfloat16* W3   = (__hip_bfloat16*)(ws + 106496);
    __hip_bfloat16* h2   = (__hip_bfloat16*)(ws + 1155072);

    k_reconstruct<<<(577536 + 255) / 256, 256, 0, stream>>>(
        w1, w2, w3, hi1, hi2, hi3, s1, s2, s3, wc1b, wc1s, wc2b, W3);
    k_conv<<<B / 4, 512, 0, stream>>>(x, wc1b, wc1s, wc2b, b1, b2, h2);
    k_fc<<<B / 16, 1024, 0, stream>>>(h2, W3, b3, fc2w, fc2b, out);
}

// Round 8
// 163.376 us; speedup vs baseline: 1.1555x; 1.1555x over previous
//
#include <hip/hip_runtime.h>
#include <hip/hip_bf16.h>
#include <math.h>

// ---------------------------------------------------------------------------
// Sketched CNN-MNIST forward, MFMA end-to-end.
// conv1: MFMA, taps t=ki*6+kj (K=30 pad 32); even-aligned b32 A-reads; odd
//        output columns via kj-shifted weights (2nd MFMA), pool picks regs.
// conv2: R6 dataflow (wave=(pool-row, n-half): 4 img A-reads + 2 B-loads per
//        tap -> 8 MFMA; LDS-heavy beats global-heavy, measured R6 vs R7) with
//        R7's sectioned h1 layout [img*4+icgrp][pos][8ic] (2-way banks, free).
// fc:    fused fc1 (16 waves x 32-col MFMA strips, A-tile in LDS) +
//        fc2 + log_softmax (1 image/wave, full-wave shuffle reduce).
// ---------------------------------------------------------------------------

typedef __attribute__((ext_vector_type(8))) short bf16x8;
typedef __attribute__((ext_vector_type(4))) float f32x4;

static __device__ inline ushort f2bfu(float v) {
    union { __hip_bfloat16 h; ushort u; } cv;
    cv.h = __float2bfloat16(v);
    return cv.u;
}

// ws layout (bytes):
//   wc1b bf16 [32 oc][32 t]  t=ki*6+kj       [0,       2048)
//   wc1s bf16 [32 oc][32 t]  kj-shifted      [2048,    4096)
//   wc2b bf16 [64 oc][25 tap][32 ic]         [4096,    106496)
//   W3   bf16 [512][1024]                    [106496,  1155072)
//   h2   bf16 [B][1024]                      [1155072, +B*2048)

__global__ __launch_bounds__(256)
void k_reconstruct(const float* __restrict__ w1, const float* __restrict__ w2,
                   const float* __restrict__ w3,
                   const int* __restrict__ hi1, const int* __restrict__ hi2,
                   const int* __restrict__ hi3,
                   const float* __restrict__ s1, const float* __restrict__ s2,
                   const float* __restrict__ s3,
                   __hip_bfloat16* __restrict__ wc1b,
                   __hip_bfloat16* __restrict__ wc1s,
                   __hip_bfloat16* __restrict__ wc2b,
                   __hip_bfloat16* __restrict__ W3) {
    int i = blockIdx.x * blockDim.x + threadIdx.x;
    if (i < 1024) {
        int oc = i >> 5, t = i & 31;
        int ki = (t * 43) >> 8;            // t / 6
        int kj = t - 6 * ki;
        float v = 0.f;
        if (ki < 5 && kj < 5) {
            int f = ki * 5 + kj;
            v = w1[oc * 128 + hi1[f]] * s1[f];
        }
        wc1b[i] = __float2bfloat16(v);
    } else if (i < 2048) {                 // kj-shifted conv1 weights
        int j = i - 1024;
        int oc = j >> 5, t = j & 31;
        int ki = (t * 43) >> 8;
        int kj = t - 6 * ki;
        float v = 0.f;
        if (ki < 5 && kj >= 1) {           // kj in 1..5 -> real tap kj-1
            int f = ki * 5 + (kj - 1);
            v = w1[oc * 128 + hi1[f]] * s1[f];
        }
        wc1s[j] = __float2bfloat16(v);
    } else if (i < 53248) {
        int j = i - 2048;
        int oc = j / 800, r = j % 800;
        int tap = r >> 5, ic = r & 31;
        int f = ic * 25 + tap;             // original sketch index
        wc2b[j] = __float2bfloat16(w2[oc * 128 + hi2[f]] * s2[f]);
    } else if (i < 577536) {
        int j = i - 53248;
        int r = j >> 10, k = j & 1023;
        W3[j] = __float2bfloat16(w3[r * 128 + hi3[k]] * s3[k]);
    }
}

// 4 images per block, 8 waves, 3 blocks/CU (LDS 43.6 KB).
// h1 layout: section s = img*4 + (ic>>3); s_h1[s*1160 + pos*8 + (ic&7)].
__global__ __launch_bounds__(512, 6)
void k_conv(const float* __restrict__ x,
            const __hip_bfloat16* __restrict__ wc1b,
            const __hip_bfloat16* __restrict__ wc1s,
            const __hip_bfloat16* __restrict__ wc2b,
            const float* __restrict__ b1, const float* __restrict__ b2,
            __hip_bfloat16* __restrict__ h2) {
    __shared__ __align__(16) ushort s_xb[4 * 816];     // bf16 images (+pad)
    __shared__ __align__(16) ushort s_h1[16 * 1160];   // sectioned, 37.1 KB

    const int tid = threadIdx.x;
    const int b0 = blockIdx.x * 4;
    const int wave = tid >> 6, lane = tid & 63;
    const int l15 = lane & 15, quad = lane >> 4;

    // ---- stage 4 images as bf16 (coalesced float4) ----
    {
        const float4* xg = (const float4*)(x + (size_t)b0 * 784);
        for (int i = tid; i < 784; i += 512) {
            float4 v = xg[i];
            int img = i / 196;
            int pos = (i - img * 196) * 4;
            ushort* dst = &s_xb[img * 816 + pos];
            dst[0] = f2bfu(v.x); dst[1] = f2bfu(v.y);
            dst[2] = f2bfu(v.z); dst[3] = f2bfu(v.w);
        }
        if (tid < 128) {                    // zero pad (read by pad taps, w=0)
            int img = tid >> 5, k = tid & 31;
            s_xb[img * 816 + 784 + k] = 0;
        }
    }

    // conv1 B-fragments (normal + shifted) + biases (tiny, L2-resident)
    bf16x8 bw1[2], bw1s[2];
    float bb1[2];
    #pragma unroll
    for (int nt = 0; nt < 2; ++nt) {
        bw1[nt]  = *(const bf16x8*)((const ushort*)wc1b + (nt * 16 + l15) * 32 + quad * 8);
        bw1s[nt] = *(const bf16x8*)((const ushort*)wc1s + (nt * 16 + l15) * 32 + quad * 8);
        bb1[nt] = b1[nt * 16 + l15];
    }
    __syncthreads();

    // ---- conv1 via MFMA: wave = (img, half). M=576 pool-grouped, N=32 ----
    {
        const int img = wave >> 1, half = wave & 1;
        const int sub = l15 & 3;
        const ushort* srcImg = s_xb + img * 816;
        int offr[4];
        #pragma unroll
        for (int r = 0; r < 4; ++r) {
            int t = quad * 8 + 2 * r;          // even
            int row = (t * 43) >> 8;           // t / 6
            int col = t - 6 * row;             // even
            offr[r] = row * 28 + col;          // even
        }
        const int g0 = l15 >> 3, r0 = l15 & 7;
        #pragma unroll
        for (int ii = 0; ii < 18; ++ii) {
            const int i = half * 18 + ii;
            const int pb = 4 * i + (l15 >> 2);
            const int pi = (pb * 171) >> 11;   // pb / 12
            const int pj = pb - 12 * pi;
            const int base_e = (2 * pi + (sub >> 1)) * 28 + 2 * pj;   // even
            const ushort* p0 = srcImg + base_e;
            union { bf16x8 v; uint u[4]; } A;
            A.u[0] = *(const uint*)(p0 + offr[0]);
            A.u[1] = *(const uint*)(p0 + offr[1]);
            A.u[2] = *(const uint*)(p0 + offr[2]);
            A.u[3] = *(const uint*)(p0 + offr[3]);
            f32x4 z = {0.f, 0.f, 0.f, 0.f};
            f32x4 ce0 = __builtin_amdgcn_mfma_f32_16x16x32_bf16(A.v, bw1[0],  z, 0, 0, 0);
            f32x4 co0 = __builtin_amdgcn_mfma_f32_16x16x32_bf16(A.v, bw1s[0], z, 0, 0, 0);
            f32x4 ce1 = __builtin_amdgcn_mfma_f32_16x16x32_bf16(A.v, bw1[1],  z, 0, 0, 0);
            f32x4 co1 = __builtin_amdgcn_mfma_f32_16x16x32_bf16(A.v, bw1s[1], z, 0, 0, 0);
            const int pbo = 4 * i + quad;
            float m0 = fmaxf(fmaxf(ce0[0], co0[1]), fmaxf(ce0[2], co0[3]));
            float m1 = fmaxf(fmaxf(ce1[0], co1[1]), fmaxf(ce1[2], co1[3]));
            // oc = l15 -> section img*4 + g0 ; oc = 16+l15 -> section img*4+2+g0
            s_h1[(img * 4 + g0) * 1160 + pbo * 8 + r0]     = f2bfu(fmaxf(m0 + bb1[0], 0.f));
            s_h1[(img * 4 + 2 + g0) * 1160 + pbo * 8 + r0] = f2bfu(fmaxf(m1 + bb1[1], 0.f));
        }
    }
    __syncthreads();

    // ---- conv2: 25 tap-GEMMs, K=ic=32; wave = (pool-row, n-half), 4 images
    //      (R6 dataflow: 4 A ds_reads + 2 B global loads -> 8 MFMA per tap) ----
    const int pr = wave >> 1, nh = wave & 1;
    const int sub2 = l15 & 3;
    const int ci2 = 2 * pr + (sub2 >> 1);
    const int cj2 = 2 * (l15 >> 2) + (sub2 & 1);
    const int posBase = (ci2 * 12 + cj2) * 8;
    const ushort* bP = (const ushort*)wc2b + quad * 8;

    f32x4 acc[4][2];                       // [img][ntl]
    float bb2[2];
    #pragma unroll
    for (int ntl = 0; ntl < 2; ++ntl) {
        bb2[ntl] = b2[(nh * 2 + ntl) * 16 + l15];
        #pragma unroll
        for (int img = 0; img < 4; ++img)
            acc[img][ntl] = (f32x4){0.f, 0.f, 0.f, 0.f};
    }

    #pragma unroll
    for (int tap = 0; tap < 25; ++tap) {
        const int ki = tap / 5, kj = tap % 5;          // compile-time
        const int off = (ki * 12 + kj) * 8;
        bf16x8 a[4];
        #pragma unroll
        for (int img = 0; img < 4; ++img)
            a[img] = *(const bf16x8*)&s_h1[(img * 4 + quad) * 1160 + posBase + off];
        #pragma unroll
        for (int ntl = 0; ntl < 2; ++ntl) {
            bf16x8 bf = *(const bf16x8*)(bP + ((nh * 2 + ntl) * 16 + l15) * 800 + tap * 32);
            #pragma unroll
            for (int img = 0; img < 4; ++img)
                acc[img][ntl] = __builtin_amdgcn_mfma_f32_16x16x32_bf16(
                    a[img], bf, acc[img][ntl], 0, 0, 0);
        }
    }

    // D rows m = quad*4+r -> (pool row = pr, pool col = quad), max over r
    #pragma unroll
    for (int img = 0; img < 4; ++img)
        #pragma unroll
        for (int ntl = 0; ntl < 2; ++ntl) {
            f32x4 c = acc[img][ntl];
            float m = fmaxf(fmaxf(c[0], c[1]), fmaxf(c[2], c[3]));
            float v = fmaxf(m + bb2[ntl], 0.f);
            h2[(size_t)(b0 + img) * 1024 + ((nh * 2 + ntl) * 16 + l15) * 16 + pr * 4 + quad] =
                __float2bfloat16(v);
        }
}

// Fused fc1 (bf16 MFMA) + fc2 + log_softmax. 1024 thr = 16 waves;
// fc1: wave = 32-col strip; fc2: wave = 1 image, full-wave shuffle reduce.
__global__ __launch_bounds__(1024)
void k_fc(const __hip_bfloat16* __restrict__ A, const __hip_bfloat16* __restrict__ Bw,
          const float* __restrict__ b3, const float* __restrict__ fc2w,
          const float* __restrict__ fc2b, float* __restrict__ out) {
    __shared__ __align__(16) ushort s_A[16 * 1032];   // +8 pad per row
    __shared__ float s_h3[16 * 516];

    const int tid = threadIdx.x;
    const int wave = tid >> 6, lane = tid & 63;
    const int l15 = lane & 15, quad = lane >> 4;
    const int mBase = blockIdx.x * 16;
    const int nBase = wave * 32;

    // stage A row `wave` into LDS (64 lanes x 32 B = 2 KB row)
    {
        const uint4* g = (const uint4*)(A + (size_t)(mBase + wave) * 1024);
        uint4 v0 = g[lane * 2], v1 = g[lane * 2 + 1];
        uint4* d = (uint4*)&s_A[wave * 1032 + lane * 16];
        d[0] = v0; d[1] = v1;
    }
    __syncthreads();

    f32x4 acc[2];
    acc[0] = (f32x4){0.f, 0.f, 0.f, 0.f};
    acc[1] = (f32x4){0.f, 0.f, 0.f, 0.f};

    const ushort* aP = &s_A[l15 * 1032 + quad * 8];
    const __hip_bfloat16* bP = Bw + (size_t)(nBase + l15) * 1024 + quad * 8;
    #pragma unroll 4
    for (int kt = 0; kt < 32; ++kt) {
        bf16x8 a = *(const bf16x8*)(aP + kt * 32);
        bf16x8 bf0 = *(const bf16x8*)(bP + kt * 32);
        bf16x8 bf1 = *(const bf16x8*)(bP + (size_t)16 * 1024 + kt * 32);
        acc[0] = __builtin_amdgcn_mfma_f32_16x16x32_bf16(a, bf0, acc[0], 0, 0, 0);
        acc[1] = __builtin_amdgcn_mfma_f32_16x16x32_bf16(a, bf1, acc[1], 0, 0, 0);
    }

    #pragma unroll
    for (int ntl = 0; ntl < 2; ++ntl) {
        int col = nBase + ntl * 16 + l15;
        float bb = b3[col];
        #pragma unroll
        for (int r = 0; r < 4; ++r)
            s_h3[(quad * 4 + r) * 516 + col] = fmaxf(acc[ntl][r] + bb, 0.f);
    }
    __syncthreads();

    // ---- fc2 + log_softmax: wave handles image `wave` ----
    const float* hrow = &s_h3[wave * 516];
    float4 h0 = *(const float4*)&hrow[lane * 8];
    float4 h1 = *(const float4*)&hrow[lane * 8 + 4];
    float lg[10];
    #pragma unroll
    for (int c = 0; c < 10; ++c) {
        float4 w0 = *(const float4*)&fc2w[c * 512 + lane * 8];
        float4 w1 = *(const float4*)&fc2w[c * 512 + lane * 8 + 4];
        float s = h0.x * w0.x + h0.y * w0.y + h0.z * w0.z + h0.w * w0.w
                + h1.x * w1.x + h1.y * w1.y + h1.z * w1.z + h1.w * w1.w;
        s += __shfl_down(s, 32);
        s += __shfl_down(s, 16);
        s += __shfl_down(s, 8);
        s += __shfl_down(s, 4);
        s += __shfl_down(s, 2);
        s += __shfl_down(s, 1);
        lg[c] = s;
    }
    if (lane == 0) {
        float mx = -1e30f;
        #pragma unroll
        for (int c = 0; c < 10; ++c) { lg[c] += fc2b[c]; mx = fmaxf(mx, lg[c]); }
        float sum = 0.f;
        #pragma unroll
        for (int c = 0; c < 10; ++c) sum += expf(lg[c] - mx);
        float lse = mx + logf(sum);
        #pragma unroll
        for (int c = 0; c < 10; ++c)
            out[(size_t)(mBase + wave) * 10 + c] = lg[c] - lse;
    }
}

extern "C" void kernel_launch(void* const* d_in, const int* in_sizes, int n_in,
                              void* d_out, int out_size, void* d_ws, size_t ws_size,
                              hipStream_t stream) {
    const float* x    = (const float*)d_in[0];
    const int*   hi1  = (const int*)d_in[1];
    const int*   hi2  = (const int*)d_in[2];
    const int*   hi3  = (const int*)d_in[3];
    const float* s1   = (const float*)d_in[4];
    const float* s2   = (const float*)d_in[5];
    const float* s3   = (const float*)d_in[6];
    const float* w1   = (const float*)d_in[7];
    const float* b1   = (const float*)d_in[8];
    const float* w2   = (const float*)d_in[9];
    const float* b2   = (const float*)d_in[10];
    const float* w3   = (const float*)d_in[11];
    const float* b3   = (const float*)d_in[12];
    const float* fc2w = (const float*)d_in[13];
    const float* fc2b = (const float*)d_in[14];
    float* out = (float*)d_out;

    const int B = in_sizes[0] / 784;   // 4096

    char* ws = (char*)d_ws;
    __hip_bfloat16* wc1b = (__hip_bfloat16*)(ws + 0);
    __hip_bfloat16* wc1s = (__hip_bfloat16*)(ws + 2048);
    __hip_bfloat16* wc2b = (__hip_bfloat16*)(ws + 4096);
    __hip_bfloat16* W3   = (__hip_bfloat16*)(ws + 106496);
    __hip_bfloat16* h2   = (__hip_bfloat16*)(ws + 1155072);

    k_reconstruct<<<(577536 + 255) / 256, 256, 0, stream>>>(
        w1, w2, w3, hi1, hi2, hi3, s1, s2, s3, wc1b, wc1s, wc2b, W3);
    k_conv<<<B / 4, 512, 0, stream>>>(x, wc1b, wc1s, wc2b, b1, b2, h2);
    k_fc<<<B / 16, 1024, 0, stream>>>(h2, W3, b3, fc2w, fc2b, out);
}

// Round 9
// 140.372 us; speedup vs baseline: 1.3449x; 1.1639x over previous
//
#include <hip/hip_runtime.h>
#include <hip/hip_bf16.h>
#include <math.h>

// ---------------------------------------------------------------------------
// Sketched CNN-MNIST forward, MFMA end-to-end.
// All weight matrices stored FRAGMENT-MAJOR: element (n=l15, k=quad*8+j) at
// [tile][lane][8] so every MFMA B-load is one coalesced 1 KB wave transaction
// (R8's 16-row scatter was 16 transactions/load -> VMEM-issue bound).
// conv1: MFMA, taps t=ki*6+kj (K=30 pad 32); even-aligned b32 A-reads; odd
//        output columns via kj-shifted weights (2nd MFMA), pool picks regs.
// conv2: wave=(pool-row, n-half): 4 img A-reads + 2 B-loads -> 8 MFMA per tap;
//        sectioned h1 [img*4+icgrp][pos][8ic]. 4 img/block, 3 blocks/CU.
// fc:    fused fc1 (16 waves x 32-col strips, A-tile in LDS) + fc2 + softmax.
// ---------------------------------------------------------------------------

typedef __attribute__((ext_vector_type(8))) short bf16x8;
typedef __attribute__((ext_vector_type(4))) float f32x4;

static __device__ inline ushort f2bfu(float v) {
    union { __hip_bfloat16 h; ushort u; } cv;
    cv.h = __float2bfloat16(v);
    return cv.u;
}

// ws layout (bytes):
//   wc1f bf16 [2 nt][64 lane][8]   frag-major      [0,       2048)
//   wc1s bf16 [2 nt][64 lane][8]   shifted         [2048,    4096)
//   wc2f bf16 [25 tap][4 nt][64 lane][8ic]         [4096,    106496)
//   W3f  bf16 [32 ntile][32 kt][64 lane][8]        [106496,  1155072)
//   h2   bf16 [B][1024]                            [1155072, +B*2048)

__global__ __launch_bounds__(256)
void k_reconstruct(const float* __restrict__ w1, const float* __restrict__ w2,
                   const float* __restrict__ w3,
                   const int* __restrict__ hi1, const int* __restrict__ hi2,
                   const int* __restrict__ hi3,
                   const float* __restrict__ s1, const float* __restrict__ s2,
                   const float* __restrict__ s3,
                   __hip_bfloat16* __restrict__ wc1f,
                   __hip_bfloat16* __restrict__ wc1s,
                   __hip_bfloat16* __restrict__ wc2f,
                   __hip_bfloat16* __restrict__ W3f) {
    const int t = blockIdx.x * blockDim.x + threadIdx.x;
    bf16x8 o;
    if (t < 256) {                         // conv1 normal (t<128) / shifted
        const bool shifted = t >= 128;
        const int u = t & 127;
        const int nt = u >> 6, lane = u & 63;
        const int quad = lane >> 4, l15 = lane & 15;
        const int oc = nt * 16 + l15;
        #pragma unroll
        for (int j = 0; j < 8; ++j) {
            int tt = quad * 8 + j;
            int ki = (tt * 43) >> 8;       // tt / 6
            int kj = tt - 6 * ki;
            float v = 0.f;
            if (!shifted && ki < 5 && kj < 5) {
                int f = ki * 5 + kj;
                v = w1[oc * 128 + hi1[f]] * s1[f];
            } else if (shifted && ki < 5 && kj >= 1 && kj <= 5) {
                int f = ki * 5 + (kj - 1);
                v = w1[oc * 128 + hi1[f]] * s1[f];
            }
            o[j] = (short)f2bfu(v);
        }
        *(bf16x8*)((ushort*)(shifted ? wc1s : wc1f) + (size_t)u * 8) = o;
    } else if (t < 6656) {                 // conv2: [tap][nt][lane][8ic]
        const int u = t - 256;
        const int l15 = u & 15, quad = (u >> 4) & 3;
        const int ntA = (u >> 6) & 3, tap = u >> 8;
        const int oc = ntA * 16 + l15;
        #pragma unroll
        for (int j = 0; j < 8; ++j) {
            int ic = quad * 8 + j;
            int f = ic * 25 + tap;
            o[j] = (short)f2bfu(w2[oc * 128 + hi2[f]] * s2[f]);
        }
        *(bf16x8*)((ushort*)wc2f + (size_t)u * 8) = o;
    } else if (t < 72192) {                // fc1: [ntile][kt][lane][8]
        const int u = t - 6656;
        const int l15 = u & 15, quad = (u >> 4) & 3;
        const int kt = (u >> 6) & 31, ntile = u >> 11;
        const int n = ntile * 16 + l15;
        #pragma unroll
        for (int j = 0; j < 8; ++j) {
            int k = kt * 32 + quad * 8 + j;
            o[j] = (short)f2bfu(w3[n * 128 + hi3[k]] * s3[k]);
        }
        *(bf16x8*)((ushort*)W3f + (size_t)u * 8) = o;
    }
}

// 4 images per block, 8 waves, 3 blocks/CU (LDS 43.6 KB).
// h1 layout: section s = img*4 + (ic>>3); s_h1[s*1160 + pos*8 + (ic&7)].
__global__ __launch_bounds__(512, 6)
void k_conv(const float* __restrict__ x,
            const __hip_bfloat16* __restrict__ wc1f,
            const __hip_bfloat16* __restrict__ wc1s,
            const __hip_bfloat16* __restrict__ wc2f,
            const float* __restrict__ b1, const float* __restrict__ b2,
            __hip_bfloat16* __restrict__ h2) {
    __shared__ __align__(16) ushort s_xb[4 * 816];     // bf16 images (+pad)
    __shared__ __align__(16) ushort s_h1[16 * 1160];   // sectioned, 37.1 KB

    const int tid = threadIdx.x;
    const int b0 = blockIdx.x * 4;
    const int wave = tid >> 6, lane = tid & 63;
    const int l15 = lane & 15, quad = lane >> 4;

    // ---- stage 4 images as bf16 (coalesced float4) ----
    {
        const float4* xg = (const float4*)(x + (size_t)b0 * 784);
        for (int i = tid; i < 784; i += 512) {
            float4 v = xg[i];
            int img = i / 196;
            int pos = (i - img * 196) * 4;
            ushort* dst = &s_xb[img * 816 + pos];
            dst[0] = f2bfu(v.x); dst[1] = f2bfu(v.y);
            dst[2] = f2bfu(v.z); dst[3] = f2bfu(v.w);
        }
        if (tid < 128) {                    // zero pad (read by pad taps, w=0)
            int img = tid >> 5, k = tid & 31;
            s_xb[img * 816 + 784 + k] = 0;
        }
    }

    // conv1 B-fragments (frag-major: coalesced 1 KB wave loads)
    bf16x8 bw1[2], bw1s[2];
    float bb1[2];
    #pragma unroll
    for (int nt = 0; nt < 2; ++nt) {
        bw1[nt]  = *(const bf16x8*)((const ushort*)wc1f + (nt * 64 + lane) * 8);
        bw1s[nt] = *(const bf16x8*)((const ushort*)wc1s + (nt * 64 + lane) * 8);
        bb1[nt] = b1[nt * 16 + l15];
    }
    __syncthreads();

    // ---- conv1 via MFMA: wave = (img, half). M=576 pool-grouped, N=32 ----
    {
        const int img = wave >> 1, half = wave & 1;
        const int sub = l15 & 3;
        const ushort* srcImg = s_xb + img * 816;
        int offr[4];
        #pragma unroll
        for (int r = 0; r < 4; ++r) {
            int t = quad * 8 + 2 * r;          // even
            int row = (t * 43) >> 8;           // t / 6
            int col = t - 6 * row;             // even
            offr[r] = row * 28 + col;          // even
        }
        const int g0 = l15 >> 3, r0 = l15 & 7;
        #pragma unroll
        for (int ii = 0; ii < 18; ++ii) {
            const int i = half * 18 + ii;
            const int pb = 4 * i + (l15 >> 2);
            const int pi = (pb * 171) >> 11;   // pb / 12
            const int pj = pb - 12 * pi;
            const int base_e = (2 * pi + (sub >> 1)) * 28 + 2 * pj;   // even
            const ushort* p0 = srcImg + base_e;
            union { bf16x8 v; uint u[4]; } A;
            A.u[0] = *(const uint*)(p0 + offr[0]);
            A.u[1] = *(const uint*)(p0 + offr[1]);
            A.u[2] = *(const uint*)(p0 + offr[2]);
            A.u[3] = *(const uint*)(p0 + offr[3]);
            f32x4 z = {0.f, 0.f, 0.f, 0.f};
            f32x4 ce0 = __builtin_amdgcn_mfma_f32_16x16x32_bf16(A.v, bw1[0],  z, 0, 0, 0);
            f32x4 co0 = __builtin_amdgcn_mfma_f32_16x16x32_bf16(A.v, bw1s[0], z, 0, 0, 0);
            f32x4 ce1 = __builtin_amdgcn_mfma_f32_16x16x32_bf16(A.v, bw1[1],  z, 0, 0, 0);
            f32x4 co1 = __builtin_amdgcn_mfma_f32_16x16x32_bf16(A.v, bw1s[1], z, 0, 0, 0);
            const int pbo = 4 * i + quad;
            float m0 = fmaxf(fmaxf(ce0[0], co0[1]), fmaxf(ce0[2], co0[3]));
            float m1 = fmaxf(fmaxf(ce1[0], co1[1]), fmaxf(ce1[2], co1[3]));
            // oc = l15 -> section img*4 + g0 ; oc = 16+l15 -> section img*4+2+g0
            s_h1[(img * 4 + g0) * 1160 + pbo * 8 + r0]     = f2bfu(fmaxf(m0 + bb1[0], 0.f));
            s_h1[(img * 4 + 2 + g0) * 1160 + pbo * 8 + r0] = f2bfu(fmaxf(m1 + bb1[1], 0.f));
        }
    }
    __syncthreads();

    // ---- conv2: 25 tap-GEMMs, K=ic=32; wave = (pool-row, n-half), 4 images
    //      4 A ds_reads + 2 coalesced B loads -> 8 MFMA per tap ----
    const int pr = wave >> 1, nh = wave & 1;
    const int sub2 = l15 & 3;
    const int ci2 = 2 * pr + (sub2 >> 1);
    const int cj2 = 2 * (l15 >> 2) + (sub2 & 1);
    const int posBase = (ci2 * 12 + cj2) * 8;

    f32x4 acc[4][2];                       // [img][ntl]
    float bb2[2];
    #pragma unroll
    for (int ntl = 0; ntl < 2; ++ntl) {
        bb2[ntl] = b2[(nh * 2 + ntl) * 16 + l15];
        #pragma unroll
        for (int img = 0; img < 4; ++img)
            acc[img][ntl] = (f32x4){0.f, 0.f, 0.f, 0.f};
    }

    #pragma unroll
    for (int tap = 0; tap < 25; ++tap) {
        const int ki = tap / 5, kj = tap % 5;          // compile-time
        const int off = (ki * 12 + kj) * 8;
        bf16x8 a[4];
        #pragma unroll
        for (int img = 0; img < 4; ++img)
            a[img] = *(const bf16x8*)&s_h1[(img * 4 + quad) * 1160 + posBase + off];
        #pragma unroll
        for (int ntl = 0; ntl < 2; ++ntl) {
            bf16x8 bf = *(const bf16x8*)((const ushort*)wc2f +
                          ((tap * 4 + nh * 2 + ntl) * 64 + lane) * 8);
            #pragma unroll
            for (int img = 0; img < 4; ++img)
                acc[img][ntl] = __builtin_amdgcn_mfma_f32_16x16x32_bf16(
                    a[img], bf, acc[img][ntl], 0, 0, 0);
        }
    }

    // D rows m = quad*4+r -> (pool row = pr, pool col = quad), max over r
    #pragma unroll
    for (int img = 0; img < 4; ++img)
        #pragma unroll
        for (int ntl = 0; ntl < 2; ++ntl) {
            f32x4 c = acc[img][ntl];
            float m = fmaxf(fmaxf(c[0], c[1]), fmaxf(c[2], c[3]));
            float v = fmaxf(m + bb2[ntl], 0.f);
            h2[(size_t)(b0 + img) * 1024 + ((nh * 2 + ntl) * 16 + l15) * 16 + pr * 4 + quad] =
                __float2bfloat16(v);
        }
}

// Fused fc1 (bf16 MFMA) + fc2 + log_softmax. 1024 thr = 16 waves;
// fc1: wave = 32-col strip (2 n-tiles), B frag-major coalesced;
// fc2: wave = 1 image, full-wave shuffle reduce.
__global__ __launch_bounds__(1024)
void k_fc(const __hip_bfloat16* __restrict__ A, const __hip_bfloat16* __restrict__ W3f,
          const float* __restrict__ b3, const float* __restrict__ fc2w,
          const float* __restrict__ fc2b, float* __restrict__ out) {
    __shared__ __align__(16) ushort s_A[16 * 1032];   // +8 pad per row
    __shared__ float s_h3[16 * 516];

    const int tid = threadIdx.x;
    const int wave = tid >> 6, lane = tid & 63;
    const int l15 = lane & 15, quad = lane >> 4;
    const int mBase = blockIdx.x * 16;

    // stage A row `wave` into LDS (64 lanes x 32 B = 2 KB row)
    {
        const uint4* g = (const uint4*)(A + (size_t)(mBase + wave) * 1024);
        uint4 v0 = g[lane * 2], v1 = g[lane * 2 + 1];
        uint4* d = (uint4*)&s_A[wave * 1032 + lane * 16];
        d[0] = v0; d[1] = v1;
    }
    __syncthreads();

    f32x4 acc[2];
    acc[0] = (f32x4){0.f, 0.f, 0.f, 0.f};
    acc[1] = (f32x4){0.f, 0.f, 0.f, 0.f};

    const ushort* aP = &s_A[l15 * 1032 + quad * 8];
    const ushort* bP0 = (const ushort*)W3f + (((size_t)(wave * 2)     * 32) * 64 + lane) * 8;
    const ushort* bP1 = (const ushort*)W3f + (((size_t)(wave * 2 + 1) * 32) * 64 + lane) * 8;
    #pragma unroll 4
    for (int kt = 0; kt < 32; ++kt) {
        bf16x8 a = *(const bf16x8*)(aP + kt * 32);
        bf16x8 bf0 = *(const bf16x8*)(bP0 + kt * 512);
        bf16x8 bf1 = *(const bf16x8*)(bP1 + kt * 512);
        acc[0] = __builtin_amdgcn_mfma_f32_16x16x32_bf16(a, bf0, acc[0], 0, 0, 0);
        acc[1] = __builtin_amdgcn_mfma_f32_16x16x32_bf16(a, bf1, acc[1], 0, 0, 0);
    }

    #pragma unroll
    for (int ntl = 0; ntl < 2; ++ntl) {
        int col = wave * 32 + ntl * 16 + l15;
        float bb = b3[col];
        #pragma unroll
        for (int r = 0; r < 4; ++r)
            s_h3[(quad * 4 + r) * 516 + col] = fmaxf(acc[ntl][r] + bb, 0.f);
    }
    __syncthreads();

    // ---- fc2 + log_softmax: wave handles image `wave` ----
    const float* hrow = &s_h3[wave * 516];
    float4 h0 = *(const float4*)&hrow[lane * 8];
    float4 h1 = *(const float4*)&hrow[lane * 8 + 4];
    float lg[10];
    #pragma unroll
    for (int c = 0; c < 10; ++c) {
        float4 w0 = *(const float4*)&fc2w[c * 512 + lane * 8];
        float4 w1 = *(const float4*)&fc2w[c * 512 + lane * 8 + 4];
        float s = h0.x * w0.x + h0.y * w0.y + h0.z * w0.z + h0.w * w0.w
                + h1.x * w1.x + h1.y * w1.y + h1.z * w1.z + h1.w * w1.w;
        s += __shfl_down(s, 32);
        s += __shfl_down(s, 16);
        s += __shfl_down(s, 8);
        s += __shfl_down(s, 4);
        s += __shfl_down(s, 2);
        s += __shfl_down(s, 1);
        lg[c] = s;
    }
    if (lane == 0) {
        float mx = -1e30f;
        #pragma unroll
        for (int c = 0; c < 10; ++c) { lg[c] += fc2b[c]; mx = fmaxf(mx, lg[c]); }
        float sum = 0.f;
        #pragma unroll
        for (int c = 0; c < 10; ++c) sum += expf(lg[c] - mx);
        float lse = mx + logf(sum);
        #pragma unroll
        for (int c = 0; c < 10; ++c)
            out[(size_t)(mBase + wave) * 10 + c] = lg[c] - lse;
    }
}

extern "C" void kernel_launch(void* const* d_in, const int* in_sizes, int n_in,
                              void* d_out, int out_size, void* d_ws, size_t ws_size,
                              hipStream_t stream) {
    const float* x    = (const float*)d_in[0];
    const int*   hi1  = (const int*)d_in[1];
    const int*   hi2  = (const int*)d_in[2];
    const int*   hi3  = (const int*)d_in[3];
    const float* s1   = (const float*)d_in[4];
    const float* s2   = (const float*)d_in[5];
    const float* s3   = (const float*)d_in[6];
    const float* w1   = (const float*)d_in[7];
    const float* b1   = (const float*)d_in[8];
    const float* w2   = (const float*)d_in[9];
    const float* b2   = (const float*)d_in[10];
    const float* w3   = (const float*)d_in[11];
    const float* b3   = (const float*)d_in[12];
    const float* fc2w = (const float*)d_in[13];
    const float* fc2b = (const float*)d_in[14];
    float* out = (float*)d_out;

    const int B = in_sizes[0] / 784;   // 4096

    char* ws = (char*)d_ws;
    __hip_bfloat16* wc1f = (__hip_bfloat16*)(ws + 0);
    __hip_bfloat16* wc1s = (__hip_bfloat16*)(ws + 2048);
    __hip_bfloat16* wc2f = (__hip_bfloat16*)(ws + 4096);
    __hip_bfloat16* W3f  = (__hip_bfloat16*)(ws + 106496);
    __hip_bfloat16* h2   = (__hip_bfloat16*)(ws + 1155072);

    k_reconstruct<<<(72192 + 255) / 256, 256, 0, stream>>>(
        w1, w2, w3, hi1, hi2, hi3, s1, s2, s3, wc1f, wc1s, wc2f, W3f);
    k_conv<<<B / 4, 512, 0, stream>>>(x, wc1f, wc1s, wc2f, b1, b2, h2);
    k_fc<<<B / 16, 1024, 0, stream>>>(h2, W3f, b3, fc2w, fc2b, out);
}